// Round 1
// 265.464 us; speedup vs baseline: 2.0377x; 2.0377x over previous
//
#include <hip/hip_runtime.h>
#include <math.h>

// ---------------------------------------------------------------------------
// BitNet-style MNIST forward, fully fused, STRICT-FP32 (R4 structure) with
// TIE-NEUTRALIZED activation quantization (R14), plus R15: LDS bank-conflict
// elimination + weight-layout transposes.
//
// R15 changes (arithmetic order UNCHANGED -> bit-identical results to R14):
//  * LDS tiles padded to odd row stride 17 (s_x, s_h1, s_h2): the old stride
//    16 put 12-14 distinct rows on 2 banks (6..11-way conflicts, measured
//    2.04e8 conflict cycles ~= 67% of all CU cycles). Stride 17 is odd ->
//    distinct rows -> distinct banks -> conflict-free.
//  * w1b stored TRANSPOSED in ws ([ic*9+k][oc]): stage-C weight reads now
//    have oc at stride 1 (conflict-free) and LDS staging is a straight copy.
//  * w2 / f1 / f2 / f3 / fl stored TRANSPOSED (k-major) in ws: fused-kernel
//    lanes read contiguous 256B segments instead of 64 distinct cache lines
//    per instruction.
// ---------------------------------------------------------------------------

#define OFF_W1   0        // 16*1*3*3   = 144   (original layout)
#define OFF_W1B  144      // 16*16*3*3  = 2304  (TRANSPOSED: [ic*9+k][16 oc])
#define OFF_W2   2448     // 96*1*12*12 = 13824 (TRANSPOSED: [k=144][96 oc])
#define OFF_F1   16272    // 64*96      = 6144  (TRANSPOSED: [k=96][64 o])
#define OFF_F2   22416    // 64*64      = 4096  (TRANSPOSED: [k=64][64 o])
#define OFF_F3   26512    // 64*64      = 4096  (TRANSPOSED: [k=64][64 o])
#define OFF_FL   30608    // 10*64      = 640   (TRANSPOSED: [k=64][10 o])

#define EPS_TIE  3e-5f    // code-units half-width of the tie band

// Tie-neutralized quantized real value for v >= 0 (post-ReLU / normed >= 0).
__device__ __forceinline__ float quantq(float v, float s) {
    const float u  = __fmul_rn(v, s);
    const float fl = floorf(u);
    const float fr = __fsub_rn(u, fl);                 // exact
    float q;
    if (fabsf(__fsub_rn(fr, 0.5f)) < EPS_TIE) q = __fadd_rn(fl, 0.5f);
    else                                      q = rintf(u);
    q = fminf(q, 127.f);
    return __fdiv_rn(q, s);
}

// numpy pairwise leaf (n <= 128): 8 unrolled accumulators over |p[i]|.
__device__ __forceinline__ float leaf_abs_sum(const float* __restrict__ p, int n) {
    float r[8];
    #pragma unroll
    for (int j = 0; j < 8; ++j) r[j] = fabsf(p[j]);
    const int nb = n & ~7;
    for (int i = 8; i < nb; i += 8) {
        #pragma unroll
        for (int j = 0; j < 8; ++j) r[j] = __fadd_rn(r[j], fabsf(p[i + j]));
    }
    float c = __fadd_rn(__fadd_rn(__fadd_rn(r[0], r[1]), __fadd_rn(r[2], r[3])),
                        __fadd_rn(__fadd_rn(r[4], r[5]), __fadd_rn(r[6], r[7])));
    for (int i = nb; i < n; ++i) c = __fadd_rn(c, fabsf(p[i]));
    return c;
}

// ---------------------------------------------------------------------------
// Weight quantization: 7 blocks, one per tensor. Values identical to R4/R14;
// only the DESTINATION layout changed (transposed, k-major) for tensors read
// strided by the fused kernel. K = source row length, W = out (oc) count;
// K==0 means keep original layout.
// ---------------------------------------------------------------------------
__global__ __launch_bounds__(256) void wq_kernel(
    const float* __restrict__ w1, const float* __restrict__ w1b,
    const float* __restrict__ w2, const float* __restrict__ f1,
    const float* __restrict__ f2, const float* __restrict__ f3,
    const float* __restrict__ fl, float* __restrict__ ws)
{
    __shared__ float red[256];
    __shared__ float ls[128];
    const int blk = blockIdx.x, t = threadIdx.x;

    const float* src; int n; int mode; int off; int K; int W;
    switch (blk) {
        case 0:  src = w1;  n = 144;   mode = 0; off = OFF_W1;  K = 0;   W = 0;  break;
        case 1:  src = w1b; n = 2304;  mode = 0; off = OFF_W1B; K = 144; W = 16; break;
        case 2:  src = w2;  n = 13824; mode = 1; off = OFF_W2;  K = 144; W = 96; break;
        case 3:  src = f1;  n = 6144;  mode = 1; off = OFF_F1;  K = 96;  W = 64; break;
        case 4:  src = f2;  n = 4096;  mode = 1; off = OFF_F2;  K = 64;  W = 64; break;
        case 5:  src = f3;  n = 4096;  mode = 1; off = OFF_F3;  K = 64;  W = 64; break;
        default: src = fl;  n = 640;   mode = 1; off = OFF_FL;  K = 64;  W = 10; break;
    }

    if (mode == 0) {
        float p = 0.f;
        for (int i = t; i < n; i += 256) p = fmaxf(p, fabsf(src[i]));
        red[t] = p;
        __syncthreads();
        for (int s = 128; s > 0; s >>= 1) {
            if (t < s) red[t] = fmaxf(red[t], red[t + s]);
            __syncthreads();
        }
        const float s = __fdiv_rn(127.0f, fmaxf(red[0], 1e-5f));
        for (int i = t; i < n; i += 256) {
            float q = rintf(__fmul_rn(src[i], s));
            q = fminf(fmaxf(q, -128.f), 127.f);
            const int d = (K == 0) ? i : (i % K) * W + (i / K);
            ws[off + d] = __fdiv_rn(q, s);
        }
    } else {
        int nleaf, loff, lsz;
        switch (n) {
            case 13824: nleaf = 128; loff = (t >> 1) * 216 + (t & 1) * 104;
                        lsz = (t & 1) ? 112 : 104; break;
            case 6144:  nleaf = 64;  loff = t * 96;  lsz = 96;  break;
            case 4096:  nleaf = 32;  loff = t * 128; lsz = 128; break;
            default:    nleaf = 8;   loff = t * 80;  lsz = 80;  break;  // 640
        }
        if (t < nleaf) ls[t] = leaf_abs_sum(src + loff, lsz);
        __syncthreads();
        for (int m = nleaf >> 1; m >= 1; m >>= 1) {
            float v = 0.f;
            if (t < m) v = __fadd_rn(ls[2 * t], ls[2 * t + 1]);
            __syncthreads();
            if (t < m) ls[t] = v;
            __syncthreads();
        }
        const float alpha = __fdiv_rn(ls[0], (float)n);
        for (int i = t; i < n; i += 256) {
            const float w = src[i];
            const float sg = (w > 0.f) ? 1.f : ((w < 0.f) ? -1.f : 0.f);
            const int d = (i % K) * W + (i / K);
            ws[off + d] = __fmul_rn(sg, alpha);
        }
    }
}

// ---------------------------------------------------------------------------
// Fused forward: one block (256 threads) per image, strict fp32.
// LDS tiles padded to stride 17 (odd) -> bank-conflict-free row accesses.
// ---------------------------------------------------------------------------
__global__ __launch_bounds__(256) void fused_kernel(
    const float* __restrict__ x, const float* __restrict__ ws,
    float* __restrict__ out)
{
    __shared__ float s_w1[144];
    __shared__ float s_w1bT[2304];       // [ic*9+k][16 oc], straight copy from ws
    __shared__ float s_x[16][17];
    __shared__ float s_h1[16][14][17];
    __shared__ float s_h2[16][12][17];
    __shared__ float s_v96[96];
    __shared__ float s_t96[96];
    __shared__ float s_q[96];
    __shared__ float s_v64[64];
    __shared__ float s_r8[8];
    __shared__ float s_bc;

    const int b = blockIdx.x;
    const int t = threadIdx.x;

    for (int i = t; i < 144;  i += 256) s_w1[i]   = ws[OFF_W1 + i];
    for (int i = t; i < 2304; i += 256) s_w1bT[i] = ws[OFF_W1B + i];

    // ---- Stage A: input act-quant (accumulation-free -> hard round) ----
    {
        const float v = x[b * 256 + t];
        float m = fabsf(v);
        #pragma unroll
        for (int msk = 8; msk >= 1; msk >>= 1) m = fmaxf(m, __shfl_xor(m, msk, 16));
        const float s = __fdiv_rn(127.0f, fmaxf(m, 1e-5f));
        float q = rintf(__fmul_rn(v, s));
        q = fminf(fmaxf(q, -128.f), 127.f);
        s_x[t >> 4][t & 15] = __fdiv_rn(q, s);
    }
    __syncthreads();

    // ---- Stage B: conv1 (1->16, 3x3) + ReLU + row quant (tie-neutral) ----
    if (t < 224) {
        const int oc = t / 14, oh = t % 14;
        float w[9];
        #pragma unroll
        for (int k = 0; k < 9; ++k) w[k] = s_w1[oc * 9 + k];
        float row[14], mx = 0.f;
        #pragma unroll
        for (int ow = 0; ow < 14; ++ow) {
            float acc = 0.f;
            #pragma unroll
            for (int kh = 0; kh < 3; ++kh)
                #pragma unroll
                for (int kw = 0; kw < 3; ++kw)
                    acc = __fmaf_rn(s_x[oh + kh][ow + kw], w[kh * 3 + kw], acc);
            acc = fmaxf(acc, 0.f);
            row[ow] = acc; mx = fmaxf(mx, acc);
        }
        const float s = __fdiv_rn(127.0f, fmaxf(mx, 1e-5f));
        #pragma unroll
        for (int ow = 0; ow < 14; ++ow)
            s_h1[oc][oh][ow] = quantq(row[ow], s);
    }
    __syncthreads();

    // ---- Stage C: conv1b (16->16, 3x3) + ReLU + row quant (tie-neutral) ----
    if (t < 192) {
        const int oc = t / 12, oh = t % 12;
        float acc[12];
        #pragma unroll
        for (int i = 0; i < 12; ++i) acc[i] = 0.f;
        for (int ic = 0; ic < 16; ++ic) {
            #pragma unroll
            for (int kh = 0; kh < 3; ++kh) {
                float A[14];
                #pragma unroll
                for (int j = 0; j < 14; ++j) A[j] = s_h1[ic][oh + kh][j];
                #pragma unroll
                for (int kw = 0; kw < 3; ++kw) {
                    const float w = s_w1bT[(ic * 9 + kh * 3 + kw) * 16 + oc];
                    #pragma unroll
                    for (int ow = 0; ow < 12; ++ow)
                        acc[ow] = __fmaf_rn(A[ow + kw], w, acc[ow]);
                }
            }
        }
        float mx = 0.f;
        #pragma unroll
        for (int ow = 0; ow < 12; ++ow) { acc[ow] = fmaxf(acc[ow], 0.f); mx = fmaxf(mx, acc[ow]); }
        const float s = __fdiv_rn(127.0f, fmaxf(mx, 1e-5f));
        #pragma unroll
        for (int ow = 0; ow < 12; ++ow)
            s_h2[oc][oh][ow] = quantq(acc[ow], s);
    }
    __syncthreads();

    // ---- Stage D: conv2 grouped binary (16 groups x 6 oc, 12x12) + ReLU ----
    if (t < 96) {
        const int g = t / 6;
        const float* wp = ws + OFF_W2;           // transposed: [k=144][96 oc]
        float acc = 0.f;
        #pragma unroll
        for (int r = 0; r < 12; ++r)
            #pragma unroll
            for (int c = 0; c < 12; ++c)
                acc = __fmaf_rn(s_h2[g][r][c], wp[(r * 12 + c) * 96 + t], acc);
        s_v96[t] = fmaxf(acc, 0.f);
    }
    __syncthreads();

    // ================= Stage E: fc1 (96->64) =================
    if (t < 96) s_t96[t] = __fmul_rn(s_v96[t], s_v96[t]);
    __syncthreads();
    if (t < 8) {
        float r = s_t96[t];
        for (int i = 8; i < 96; i += 8) r = __fadd_rn(r, s_t96[i + t]);
        s_r8[t] = r;
    }
    __syncthreads();
    if (t == 0) {
        const float c = __fadd_rn(
            __fadd_rn(__fadd_rn(s_r8[0], s_r8[1]), __fadd_rn(s_r8[2], s_r8[3])),
            __fadd_rn(__fadd_rn(s_r8[4], s_r8[5]), __fadd_rn(s_r8[6], s_r8[7])));
        const float mean = __fdiv_rn(c, 96.0f);
        s_bc = __fdiv_rn(1.0f, __fsqrt_rn(__fadd_rn(mean, 1e-6f)));
    }
    __syncthreads();
    if (t < 96) s_t96[t] = __fmul_rn(s_v96[t], s_bc);
    __syncthreads();
    if (t < 64) {
        float m = s_t96[t];
        if (t < 32) m = fmaxf(m, s_t96[64 + t]);
        #pragma unroll
        for (int msk = 32; msk >= 1; msk >>= 1) m = fmaxf(m, __shfl_xor(m, msk, 64));
        if (t == 0) s_bc = __fdiv_rn(127.0f, fmaxf(m, 1e-5f));
    }
    __syncthreads();
    if (t < 96) s_q[t] = quantq(s_t96[t], s_bc);    // tie-neutral
    __syncthreads();
    if (t < 64) {
        const float* wp = ws + OFF_F1;           // transposed: [k=96][64 o]
        float acc = 0.f;
        for (int k = 0; k < 96; ++k) acc = __fmaf_rn(s_q[k], wp[k * 64 + t], acc);
        s_v64[t] = fmaxf(acc, 0.f);
    }
    __syncthreads();

    // ================= Stages F,G: fc2, fc3 (64->64) =================
    #pragma unroll 1
    for (int stage = 0; stage < 2; ++stage) {
        const int woff = stage == 0 ? OFF_F2 : OFF_F3;
        if (t < 64) s_t96[t] = __fmul_rn(s_v64[t], s_v64[t]);
        __syncthreads();
        if (t < 8) {
            float r = s_t96[t];
            for (int i = 8; i < 64; i += 8) r = __fadd_rn(r, s_t96[i + t]);
            s_r8[t] = r;
        }
        __syncthreads();
        if (t == 0) {
            const float c = __fadd_rn(
                __fadd_rn(__fadd_rn(s_r8[0], s_r8[1]), __fadd_rn(s_r8[2], s_r8[3])),
                __fadd_rn(__fadd_rn(s_r8[4], s_r8[5]), __fadd_rn(s_r8[6], s_r8[7])));
            const float mean = __fdiv_rn(c, 64.0f);
            s_bc = __fdiv_rn(1.0f, __fsqrt_rn(__fadd_rn(mean, 1e-6f)));
        }
        __syncthreads();
        if (t < 64) s_t96[t] = __fmul_rn(s_v64[t], s_bc);
        __syncthreads();
        if (t < 64) {
            float m = s_t96[t];
            #pragma unroll
            for (int msk = 32; msk >= 1; msk >>= 1) m = fmaxf(m, __shfl_xor(m, msk, 64));
            if (t == 0) s_bc = __fdiv_rn(127.0f, fmaxf(m, 1e-5f));
        }
        __syncthreads();
        if (t < 64) s_q[t] = quantq(s_t96[t], s_bc);    // tie-neutral
        __syncthreads();
        if (t < 64) {
            const float* wp = ws + woff;         // transposed: [k=64][64 o]
            float acc = 0.f;
            for (int k = 0; k < 64; ++k) acc = __fmaf_rn(s_q[k], wp[k * 64 + t], acc);
            s_v64[t] = fmaxf(acc, 0.f);
        }
        __syncthreads();
    }

    // ================= Stage H: fcl (64->10), no ReLU =================
    if (t < 64) s_t96[t] = __fmul_rn(s_v64[t], s_v64[t]);
    __syncthreads();
    if (t < 8) {
        float r = s_t96[t];
        for (int i = 8; i < 64; i += 8) r = __fadd_rn(r, s_t96[i + t]);
        s_r8[t] = r;
    }
    __syncthreads();
    if (t == 0) {
        const float c = __fadd_rn(
            __fadd_rn(__fadd_rn(s_r8[0], s_r8[1]), __fadd_rn(s_r8[2], s_r8[3])),
            __fadd_rn(__fadd_rn(s_r8[4], s_r8[5]), __fadd_rn(s_r8[6], s_r8[7])));
        const float mean = __fdiv_rn(c, 64.0f);
        s_bc = __fdiv_rn(1.0f, __fsqrt_rn(__fadd_rn(mean, 1e-6f)));
    }
    __syncthreads();
    if (t < 64) s_t96[t] = __fmul_rn(s_v64[t], s_bc);
    __syncthreads();
    if (t < 64) {
        float m = s_t96[t];
        #pragma unroll
        for (int msk = 32; msk >= 1; msk >>= 1) m = fmaxf(m, __shfl_xor(m, msk, 64));
        if (t == 0) s_bc = __fdiv_rn(127.0f, fmaxf(m, 1e-5f));
    }
    __syncthreads();
    if (t < 64) s_q[t] = quantq(s_t96[t], s_bc);        // tie-neutral
    __syncthreads();
    if (t < 10) {
        const float* wp = ws + OFF_FL;           // transposed: [k=64][10 o]
        float acc = 0.f;
        for (int k = 0; k < 64; ++k) acc = __fmaf_rn(s_q[k], wp[k * 10 + t], acc);
        out[b * 10 + t] = acc;
    }
}

extern "C" void kernel_launch(void* const* d_in, const int* in_sizes, int n_in,
                              void* d_out, int out_size, void* d_ws, size_t ws_size,
                              hipStream_t stream) {
    const float* x   = (const float*)d_in[0];
    const float* w1  = (const float*)d_in[1];
    const float* w1b = (const float*)d_in[2];
    const float* w2  = (const float*)d_in[3];
    const float* f1  = (const float*)d_in[4];
    const float* f2  = (const float*)d_in[5];
    const float* f3  = (const float*)d_in[6];
    const float* fl  = (const float*)d_in[7];
    float* out = (float*)d_out;
    float* ws  = (float*)d_ws;

    const int B = in_sizes[0] / 256;  // 8192

    wq_kernel<<<7, 256, 0, stream>>>(w1, w1b, w2, f1, f2, f3, fl, ws);
    fused_kernel<<<B, 256, 0, stream>>>(x, ws, out);
}

// Round 2
// 264.372 us; speedup vs baseline: 2.0461x; 1.0041x over previous
//
#include <hip/hip_runtime.h>
#include <math.h>

// ---------------------------------------------------------------------------
// BitNet-style MNIST forward, fully fused, STRICT-FP32 (R4 structure) with
// TIE-NEUTRALIZED activation quantization (R14) + R15 (bank-conflict fix)
// + R16: LDS *throughput* optimization.
//
// R16 changes (arithmetic order UNCHANGED -> bit-identical results):
//  * LDS activation tiles padded to stride 20 (16B-aligned rows) and all hot
//    row accesses converted to ds_read_b128/ds_write_b128 (explicit float4).
//    Stride 17 (R15) killed conflicts but forced scalar b32 streams: stage C
//    alone issued ~816 ds_read_b32 per thread (~17k LDS-pipe cycles/image ~=
//    the whole 15.7k cycle/image budget). b128 cuts insts 3.5x, cycles ~2.4x.
//    Stride-20 rows cycle through 8 distinct bank-quads; residual aliasing is
//    <=2-way on b128 = data-minimum (free).
//  * conv1/conv1b weights NO LONGER STAGED IN LDS: read directly from ws
//    (L1-resident, ~13KB, VMEM pipe was idle). Removes 144 ds_reads/thread
//    from the saturated LDS pipe AND shrinks LDS to 36,004B, preserving
//    4 blocks/CU (stride-20 pads alone would have crossed the 40,960B
//    boundary to 3 blocks/CU).
//  * w1/w1b repacked in ws as [oc][ic*12+k] (pad 9->12) so per-ic weight
//    fetch is 2x float4 + 1x float, 16B-aligned.
// ---------------------------------------------------------------------------

#define OFF_W1   0        // 16 oc x 12      = 192   ([oc][k], k padded 9->12)
#define OFF_W1B  192      // 16 oc x 16 x 12 = 3072  ([oc][ic*12+k])
#define OFF_W2   3264     // 96*1*12*12 = 13824 (TRANSPOSED: [k=144][96 oc])
#define OFF_F1   17088    // 64*96      = 6144  (TRANSPOSED: [k=96][64 o])
#define OFF_F2   23232    // 64*64      = 4096  (TRANSPOSED: [k=64][64 o])
#define OFF_F3   27328    // 64*64      = 4096  (TRANSPOSED: [k=64][64 o])
#define OFF_FL   31424    // 10*64      = 640   (TRANSPOSED: [k=64][10 o])

#define EPS_TIE  3e-5f    // code-units half-width of the tie band

// Tie-neutralized quantized real value for v >= 0 (post-ReLU / normed >= 0).
__device__ __forceinline__ float quantq(float v, float s) {
    const float u  = __fmul_rn(v, s);
    const float fl = floorf(u);
    const float fr = __fsub_rn(u, fl);                 // exact
    float q;
    if (fabsf(__fsub_rn(fr, 0.5f)) < EPS_TIE) q = __fadd_rn(fl, 0.5f);
    else                                      q = rintf(u);
    q = fminf(q, 127.f);
    return __fdiv_rn(q, s);
}

// numpy pairwise leaf (n <= 128): 8 unrolled accumulators over |p[i]|.
__device__ __forceinline__ float leaf_abs_sum(const float* __restrict__ p, int n) {
    float r[8];
    #pragma unroll
    for (int j = 0; j < 8; ++j) r[j] = fabsf(p[j]);
    const int nb = n & ~7;
    for (int i = 8; i < nb; i += 8) {
        #pragma unroll
        for (int j = 0; j < 8; ++j) r[j] = __fadd_rn(r[j], fabsf(p[i + j]));
    }
    float c = __fadd_rn(__fadd_rn(__fadd_rn(r[0], r[1]), __fadd_rn(r[2], r[3])),
                        __fadd_rn(__fadd_rn(r[4], r[5]), __fadd_rn(r[6], r[7])));
    for (int i = nb; i < n; ++i) c = __fadd_rn(c, fabsf(p[i]));
    return c;
}

// ---------------------------------------------------------------------------
// Weight quantization: 7 blocks, one per tensor. Values identical to R4/R14;
// only DESTINATION layouts changed.
//   blk0 (w1,  8bit):  d = (i/9)*12 + i%9                   [oc][k pad12]
//   blk1 (w1b, 8bit):  d = oc*192 + ic*12 + k               [oc][ic*12+k]
//   blk>=2 (binary):   d = (i%K)*W + i/K                    k-major transpose
// ---------------------------------------------------------------------------
__global__ __launch_bounds__(256) void wq_kernel(
    const float* __restrict__ w1, const float* __restrict__ w1b,
    const float* __restrict__ w2, const float* __restrict__ f1,
    const float* __restrict__ f2, const float* __restrict__ f3,
    const float* __restrict__ fl, float* __restrict__ ws)
{
    __shared__ float red[256];
    __shared__ float ls[128];
    const int blk = blockIdx.x, t = threadIdx.x;

    const float* src; int n; int mode; int off; int K; int W;
    switch (blk) {
        case 0:  src = w1;  n = 144;   mode = 0; off = OFF_W1;  K = 0;   W = 0;  break;
        case 1:  src = w1b; n = 2304;  mode = 0; off = OFF_W1B; K = 0;   W = 0;  break;
        case 2:  src = w2;  n = 13824; mode = 1; off = OFF_W2;  K = 144; W = 96; break;
        case 3:  src = f1;  n = 6144;  mode = 1; off = OFF_F1;  K = 96;  W = 64; break;
        case 4:  src = f2;  n = 4096;  mode = 1; off = OFF_F2;  K = 64;  W = 64; break;
        case 5:  src = f3;  n = 4096;  mode = 1; off = OFF_F3;  K = 64;  W = 64; break;
        default: src = fl;  n = 640;   mode = 1; off = OFF_FL;  K = 64;  W = 10; break;
    }

    if (mode == 0) {
        float p = 0.f;
        for (int i = t; i < n; i += 256) p = fmaxf(p, fabsf(src[i]));
        red[t] = p;
        __syncthreads();
        for (int s = 128; s > 0; s >>= 1) {
            if (t < s) red[t] = fmaxf(red[t], red[t + s]);
            __syncthreads();
        }
        const float s = __fdiv_rn(127.0f, fmaxf(red[0], 1e-5f));
        for (int i = t; i < n; i += 256) {
            float q = rintf(__fmul_rn(src[i], s));
            q = fminf(fmaxf(q, -128.f), 127.f);
            int d;
            if (blk == 0) d = (i / 9) * 12 + (i % 9);
            else          { const int oc = i / 144, k = i % 144;
                            d = oc * 192 + (k / 9) * 12 + (k % 9); }
            ws[off + d] = __fdiv_rn(q, s);
        }
    } else {
        int nleaf, loff, lsz;
        switch (n) {
            case 13824: nleaf = 128; loff = (t >> 1) * 216 + (t & 1) * 104;
                        lsz = (t & 1) ? 112 : 104; break;
            case 6144:  nleaf = 64;  loff = t * 96;  lsz = 96;  break;
            case 4096:  nleaf = 32;  loff = t * 128; lsz = 128; break;
            default:    nleaf = 8;   loff = t * 80;  lsz = 80;  break;  // 640
        }
        if (t < nleaf) ls[t] = leaf_abs_sum(src + loff, lsz);
        __syncthreads();
        for (int m = nleaf >> 1; m >= 1; m >>= 1) {
            float v = 0.f;
            if (t < m) v = __fadd_rn(ls[2 * t], ls[2 * t + 1]);
            __syncthreads();
            if (t < m) ls[t] = v;
            __syncthreads();
        }
        const float alpha = __fdiv_rn(ls[0], (float)n);
        for (int i = t; i < n; i += 256) {
            const float w = src[i];
            const float sg = (w > 0.f) ? 1.f : ((w < 0.f) ? -1.f : 0.f);
            const int d = (i % K) * W + (i / K);
            ws[off + d] = __fmul_rn(sg, alpha);
        }
    }
}

// ---------------------------------------------------------------------------
// Fused forward: one block (256 threads) per image, strict fp32.
// Stride-20 rows (16B aligned, bank-spread) + float4 LDS access throughout.
// ---------------------------------------------------------------------------
__global__ __launch_bounds__(256) void fused_kernel(
    const float* __restrict__ x, const float* __restrict__ ws,
    float* __restrict__ out)
{
    __shared__ __align__(16) float s_x[16][20];
    __shared__ __align__(16) float s_h1[16][14][20];
    __shared__ __align__(16) float s_h2[16][12][20];
    __shared__ float s_v96[96];
    __shared__ float s_t96[96];
    __shared__ float s_q[96];
    __shared__ float s_v64[64];
    __shared__ float s_r8[8];
    __shared__ float s_bc;

    const int b = blockIdx.x;
    const int t = threadIdx.x;

    // ---- Stage A: input act-quant (accumulation-free -> hard round) ----
    {
        const float v = x[b * 256 + t];
        float m = fabsf(v);
        #pragma unroll
        for (int msk = 8; msk >= 1; msk >>= 1) m = fmaxf(m, __shfl_xor(m, msk, 16));
        const float s = __fdiv_rn(127.0f, fmaxf(m, 1e-5f));
        float q = rintf(__fmul_rn(v, s));
        q = fminf(fmaxf(q, -128.f), 127.f);
        s_x[t >> 4][t & 15] = __fdiv_rn(q, s);
    }
    __syncthreads();

    // ---- Stage B: conv1 (1->16, 3x3) + ReLU + row quant (tie-neutral) ----
    if (t < 224) {
        const int oc = t / 14, oh = t % 14;
        const float* __restrict__ wg = ws + OFF_W1 + oc * 12;
        const float4 wv0 = *(const float4*)&wg[0];
        const float4 wv1 = *(const float4*)&wg[4];
        const float  w8  = wg[8];
        const float w[9] = {wv0.x, wv0.y, wv0.z, wv0.w,
                            wv1.x, wv1.y, wv1.z, wv1.w, w8};
        float acc[14];
        #pragma unroll
        for (int ow = 0; ow < 14; ++ow) acc[ow] = 0.f;
        #pragma unroll
        for (int kh = 0; kh < 3; ++kh) {
            float A[16];
            #pragma unroll
            for (int j4 = 0; j4 < 4; ++j4)
                *(float4*)&A[j4 * 4] = *(const float4*)&s_x[oh + kh][j4 * 4];
            #pragma unroll
            for (int kw = 0; kw < 3; ++kw) {
                const float wk = w[kh * 3 + kw];
                #pragma unroll
                for (int ow = 0; ow < 14; ++ow)
                    acc[ow] = __fmaf_rn(A[ow + kw], wk, acc[ow]);
            }
        }
        float mx = 0.f;
        #pragma unroll
        for (int ow = 0; ow < 14; ++ow) { acc[ow] = fmaxf(acc[ow], 0.f); mx = fmaxf(mx, acc[ow]); }
        const float s = __fdiv_rn(127.0f, fmaxf(mx, 1e-5f));
        float q[14];
        #pragma unroll
        for (int ow = 0; ow < 14; ++ow) q[ow] = quantq(acc[ow], s);
        *(float4*)&s_h1[oc][oh][0]  = *(const float4*)&q[0];
        *(float4*)&s_h1[oc][oh][4]  = *(const float4*)&q[4];
        *(float4*)&s_h1[oc][oh][8]  = *(const float4*)&q[8];
        *(float2*)&s_h1[oc][oh][12] = *(const float2*)&q[12];
    }
    __syncthreads();

    // ---- Stage C: conv1b (16->16, 3x3) + ReLU + row quant (tie-neutral) ----
    if (t < 192) {
        const int oc = t / 12, oh = t % 12;
        const float* __restrict__ wg = ws + OFF_W1B + oc * 192;
        float acc[12];
        #pragma unroll
        for (int i = 0; i < 12; ++i) acc[i] = 0.f;
        for (int ic = 0; ic < 16; ++ic) {
            const float4 wv0 = *(const float4*)&wg[ic * 12];
            const float4 wv1 = *(const float4*)&wg[ic * 12 + 4];
            const float  w8  = wg[ic * 12 + 8];
            const float wr[9] = {wv0.x, wv0.y, wv0.z, wv0.w,
                                 wv1.x, wv1.y, wv1.z, wv1.w, w8};
            #pragma unroll
            for (int kh = 0; kh < 3; ++kh) {
                float A[14];
                *(float4*)&A[0]  = *(const float4*)&s_h1[ic][oh + kh][0];
                *(float4*)&A[4]  = *(const float4*)&s_h1[ic][oh + kh][4];
                *(float4*)&A[8]  = *(const float4*)&s_h1[ic][oh + kh][8];
                *(float2*)&A[12] = *(const float2*)&s_h1[ic][oh + kh][12];
                #pragma unroll
                for (int kw = 0; kw < 3; ++kw) {
                    const float w = wr[kh * 3 + kw];
                    #pragma unroll
                    for (int ow = 0; ow < 12; ++ow)
                        acc[ow] = __fmaf_rn(A[ow + kw], w, acc[ow]);
                }
            }
        }
        float mx = 0.f;
        #pragma unroll
        for (int ow = 0; ow < 12; ++ow) { acc[ow] = fmaxf(acc[ow], 0.f); mx = fmaxf(mx, acc[ow]); }
        const float s = __fdiv_rn(127.0f, fmaxf(mx, 1e-5f));
        float q[12];
        #pragma unroll
        for (int ow = 0; ow < 12; ++ow) q[ow] = quantq(acc[ow], s);
        *(float4*)&s_h2[oc][oh][0] = *(const float4*)&q[0];
        *(float4*)&s_h2[oc][oh][4] = *(const float4*)&q[4];
        *(float4*)&s_h2[oc][oh][8] = *(const float4*)&q[8];
    }
    __syncthreads();

    // ---- Stage D: conv2 grouped binary (16 groups x 6 oc, 12x12) + ReLU ----
    if (t < 96) {
        const int g = t / 6;
        const float* __restrict__ wp = ws + OFF_W2;  // transposed: [k=144][96 oc]
        float acc = 0.f;
        #pragma unroll
        for (int r = 0; r < 12; ++r) {
            float A[12];
            *(float4*)&A[0] = *(const float4*)&s_h2[g][r][0];
            *(float4*)&A[4] = *(const float4*)&s_h2[g][r][4];
            *(float4*)&A[8] = *(const float4*)&s_h2[g][r][8];
            #pragma unroll
            for (int c = 0; c < 12; ++c)
                acc = __fmaf_rn(A[c], wp[(r * 12 + c) * 96 + t], acc);
        }
        s_v96[t] = fmaxf(acc, 0.f);
    }
    __syncthreads();

    // ================= Stage E: fc1 (96->64) =================
    if (t < 96) s_t96[t] = __fmul_rn(s_v96[t], s_v96[t]);
    __syncthreads();
    if (t < 8) {
        float r = s_t96[t];
        for (int i = 8; i < 96; i += 8) r = __fadd_rn(r, s_t96[i + t]);
        s_r8[t] = r;
    }
    __syncthreads();
    if (t == 0) {
        const float c = __fadd_rn(
            __fadd_rn(__fadd_rn(s_r8[0], s_r8[1]), __fadd_rn(s_r8[2], s_r8[3])),
            __fadd_rn(__fadd_rn(s_r8[4], s_r8[5]), __fadd_rn(s_r8[6], s_r8[7])));
        const float mean = __fdiv_rn(c, 96.0f);
        s_bc = __fdiv_rn(1.0f, __fsqrt_rn(__fadd_rn(mean, 1e-6f)));
    }
    __syncthreads();
    if (t < 96) s_t96[t] = __fmul_rn(s_v96[t], s_bc);
    __syncthreads();
    if (t < 64) {
        float m = s_t96[t];
        if (t < 32) m = fmaxf(m, s_t96[64 + t]);
        #pragma unroll
        for (int msk = 32; msk >= 1; msk >>= 1) m = fmaxf(m, __shfl_xor(m, msk, 64));
        if (t == 0) s_bc = __fdiv_rn(127.0f, fmaxf(m, 1e-5f));
    }
    __syncthreads();
    if (t < 96) s_q[t] = quantq(s_t96[t], s_bc);    // tie-neutral
    __syncthreads();
    if (t < 64) {
        const float* __restrict__ wp = ws + OFF_F1;  // transposed: [k=96][64 o]
        float acc = 0.f;
        for (int k = 0; k < 96; ++k) acc = __fmaf_rn(s_q[k], wp[k * 64 + t], acc);
        s_v64[t] = fmaxf(acc, 0.f);
    }
    __syncthreads();

    // ================= Stages F,G: fc2, fc3 (64->64) =================
    #pragma unroll 1
    for (int stage = 0; stage < 2; ++stage) {
        const int woff = stage == 0 ? OFF_F2 : OFF_F3;
        if (t < 64) s_t96[t] = __fmul_rn(s_v64[t], s_v64[t]);
        __syncthreads();
        if (t < 8) {
            float r = s_t96[t];
            for (int i = 8; i < 64; i += 8) r = __fadd_rn(r, s_t96[i + t]);
            s_r8[t] = r;
        }
        __syncthreads();
        if (t == 0) {
            const float c = __fadd_rn(
                __fadd_rn(__fadd_rn(s_r8[0], s_r8[1]), __fadd_rn(s_r8[2], s_r8[3])),
                __fadd_rn(__fadd_rn(s_r8[4], s_r8[5]), __fadd_rn(s_r8[6], s_r8[7])));
            const float mean = __fdiv_rn(c, 64.0f);
            s_bc = __fdiv_rn(1.0f, __fsqrt_rn(__fadd_rn(mean, 1e-6f)));
        }
        __syncthreads();
        if (t < 64) s_t96[t] = __fmul_rn(s_v64[t], s_bc);
        __syncthreads();
        if (t < 64) {
            float m = s_t96[t];
            #pragma unroll
            for (int msk = 32; msk >= 1; msk >>= 1) m = fmaxf(m, __shfl_xor(m, msk, 64));
            if (t == 0) s_bc = __fdiv_rn(127.0f, fmaxf(m, 1e-5f));
        }
        __syncthreads();
        if (t < 64) s_q[t] = quantq(s_t96[t], s_bc);    // tie-neutral
        __syncthreads();
        if (t < 64) {
            const float* __restrict__ wp = ws + woff;   // transposed: [k=64][64 o]
            float acc = 0.f;
            for (int k = 0; k < 64; ++k) acc = __fmaf_rn(s_q[k], wp[k * 64 + t], acc);
            s_v64[t] = fmaxf(acc, 0.f);
        }
        __syncthreads();
    }

    // ================= Stage H: fcl (64->10), no ReLU =================
    if (t < 64) s_t96[t] = __fmul_rn(s_v64[t], s_v64[t]);
    __syncthreads();
    if (t < 8) {
        float r = s_t96[t];
        for (int i = 8; i < 64; i += 8) r = __fadd_rn(r, s_t96[i + t]);
        s_r8[t] = r;
    }
    __syncthreads();
    if (t == 0) {
        const float c = __fadd_rn(
            __fadd_rn(__fadd_rn(s_r8[0], s_r8[1]), __fadd_rn(s_r8[2], s_r8[3])),
            __fadd_rn(__fadd_rn(s_r8[4], s_r8[5]), __fadd_rn(s_r8[6], s_r8[7])));
        const float mean = __fdiv_rn(c, 64.0f);
        s_bc = __fdiv_rn(1.0f, __fsqrt_rn(__fadd_rn(mean, 1e-6f)));
    }
    __syncthreads();
    if (t < 64) s_t96[t] = __fmul_rn(s_v64[t], s_bc);
    __syncthreads();
    if (t < 64) {
        float m = s_t96[t];
        #pragma unroll
        for (int msk = 32; msk >= 1; msk >>= 1) m = fmaxf(m, __shfl_xor(m, msk, 64));
        if (t == 0) s_bc = __fdiv_rn(127.0f, fmaxf(m, 1e-5f));
    }
    __syncthreads();
    if (t < 64) s_q[t] = quantq(s_t96[t], s_bc);        // tie-neutral
    __syncthreads();
    if (t < 10) {
        const float* __restrict__ wp = ws + OFF_FL;     // transposed: [k=64][10 o]
        float acc = 0.f;
        for (int k = 0; k < 64; ++k) acc = __fmaf_rn(s_q[k], wp[k * 10 + t], acc);
        out[b * 10 + t] = acc;
    }
}

extern "C" void kernel_launch(void* const* d_in, const int* in_sizes, int n_in,
                              void* d_out, int out_size, void* d_ws, size_t ws_size,
                              hipStream_t stream) {
    const float* x   = (const float*)d_in[0];
    const float* w1  = (const float*)d_in[1];
    const float* w1b = (const float*)d_in[2];
    const float* w2  = (const float*)d_in[3];
    const float* f1  = (const float*)d_in[4];
    const float* f2  = (const float*)d_in[5];
    const float* f3  = (const float*)d_in[6];
    const float* fl  = (const float*)d_in[7];
    float* out = (float*)d_out;
    float* ws  = (float*)d_ws;

    const int B = in_sizes[0] / 256;  // 8192

    wq_kernel<<<7, 256, 0, stream>>>(w1, w1b, w2, f1, f2, f3, fl, ws);
    fused_kernel<<<B, 256, 0, stream>>>(x, ws, out);
}